// Round 1
// baseline (1031.658 us; speedup 1.0000x reference)
//
#include <hip/hip_runtime.h>
#include <hip/hip_bf16.h>
#include <cmath>

// Problem: y = x[4096,8192] @ W[8192,8192]^T + b; avgpool16 -> gelu_tanh*2 -> rowmax
#define M_DIM 4096
#define N_DIM 8192
#define K_DIM 8192

typedef __bf16 bf16x8 __attribute__((ext_vector_type(8)));
typedef float floatx4 __attribute__((ext_vector_type(4)));

__device__ __forceinline__ unsigned short f2bf(float f) {
  unsigned int u = __float_as_uint(f);
  unsigned int r = (u + 0x7fffu + ((u >> 16) & 1u)) >> 16;  // RNE
  return (unsigned short)r;
}

__global__ void convert_f32_bf16(const float4* __restrict__ src,
                                 ushort4* __restrict__ dst, int n4) {
  int i = blockIdx.x * blockDim.x + threadIdx.x;
  int stride = gridDim.x * blockDim.x;
  for (; i < n4; i += stride) {
    float4 f = src[i];
    ushort4 o;
    o.x = f2bf(f.x); o.y = f2bf(f.y); o.z = f2bf(f.z); o.w = f2bf(f.w);
    dst[i] = o;
  }
}

__global__ void bias_pool(const float* __restrict__ b, float* __restrict__ bpool) {
  int g = threadIdx.x;  // 512 groups
  float s = 0.f;
  for (int i = 0; i < 16; ++i) s += b[g * 16 + i];
  bpool[g] = s;
}

// 128x128 tile, BK=64, 4 waves of 64x64, mfma_f32_16x16x32_bf16.
// A = x (M,K row-major), B = W (N,K row-major): C[m][n] = sum_k A[m][k]*B[n][k].
// LDS layout: [row][64 bf16] with 16B chunks XOR-swizzled by (row&7) so
// ds_read_b128 frag loads hit <=2 lanes/bank (free). global_load_lds dest is
// wave-uniform base + lane*16, so the swizzle is applied by permuting which
// global 16B chunk each lane fetches (stays within the same 128B line).
__global__ __launch_bounds__(256) void gemm_pool(
    const unsigned short* __restrict__ xb,   // [4096][8192] bf16
    const unsigned short* __restrict__ wb,   // [8192][8192] bf16
    float* __restrict__ pooled)              // [4096][512] group-sums (no bias)
{
  __shared__ __align__(16) unsigned short As[128 * 64];
  __shared__ __align__(16) unsigned short Bs[128 * 64];

  const int tid = threadIdx.x;
  const int L = tid & 63;
  const int w = tid >> 6;            // wave 0..3
  const int wm = w & 1, wn = w >> 1; // wave -> 64x64 quadrant
  const int lane15 = L & 15, quad = L >> 4;

  const int bn = blockIdx.x, bm = blockIdx.y;

  // Staging: each wave stages 32 rows of A and 32 rows of B per BK=64 iter,
  // as 4 global_load_lds_dwordx4 each (1 KB per inst: 8 rows x 128B).
  const int srow = w * 32 + (L >> 3);                 // + i*8 per inst
  const int schunk = ((L & 7) ^ ((L >> 3) & 7)) * 8;  // swizzled 16B chunk
  const unsigned short* ga = xb + (size_t)(bm * 128 + srow) * K_DIM + schunk;
  const unsigned short* gb = wb + (size_t)(bn * 128 + srow) * K_DIM + schunk;
  unsigned short* lA = As + (w * 32) * 64;
  unsigned short* lB = Bs + (w * 32) * 64;

  floatx4 acc[4][4];
#pragma unroll
  for (int t = 0; t < 4; ++t)
#pragma unroll
    for (int u = 0; u < 4; ++u) acc[t][u] = (floatx4)0.f;

  const bf16x8* Av = (const bf16x8*)As;
  const bf16x8* Bv = (const bf16x8*)Bs;

  for (int kk = 0; kk < K_DIM / 64; ++kk) {
#pragma unroll
    for (int i = 0; i < 4; ++i) {
      __builtin_amdgcn_global_load_lds(
          (const __attribute__((address_space(1))) void*)(ga + (size_t)(i * 8) * K_DIM),
          (__attribute__((address_space(3))) void*)(lA + i * 8 * 64), 16, 0, 0);
    }
#pragma unroll
    for (int i = 0; i < 4; ++i) {
      __builtin_amdgcn_global_load_lds(
          (const __attribute__((address_space(1))) void*)(gb + (size_t)(i * 8) * K_DIM),
          (__attribute__((address_space(3))) void*)(lB + i * 8 * 64), 16, 0, 0);
    }
    ga += 64; gb += 64;
    __syncthreads();  // drains vmcnt before barrier

#pragma unroll
    for (int ks = 0; ks < 2; ++ks) {
      bf16x8 af[4], bfr[4];
#pragma unroll
      for (int t = 0; t < 4; ++t) {
        int r = wm * 64 + t * 16 + lane15;
        af[t] = Av[r * 8 + ((ks * 4 + quad) ^ (lane15 & 7))];
      }
#pragma unroll
      for (int u = 0; u < 4; ++u) {
        int r = wn * 64 + u * 16 + lane15;
        bfr[u] = Bv[r * 8 + ((ks * 4 + quad) ^ (lane15 & 7))];
      }
#pragma unroll
      for (int t = 0; t < 4; ++t)
#pragma unroll
        for (int u = 0; u < 4; ++u)
          acc[t][u] = __builtin_amdgcn_mfma_f32_16x16x32_bf16(af[t], bfr[u],
                                                              acc[t][u], 0, 0, 0);
    }
    __syncthreads();
  }

  // Fused avg-pool epilogue. C/D layout: col(n) = lane&15, row(m) = quad*4+reg.
  // One 16-col MFMA tile == exactly one pool group; butterfly-sum over the 16
  // lanes of the group, then lanes 0..3 of each quad write 16 row-sums.
  const int out_row_base = bm * 128 + wm * 64;
  const int g_base = bn * 8 + wn * 4;
#pragma unroll
  for (int u = 0; u < 4; ++u) {
#pragma unroll
    for (int t = 0; t < 4; ++t) {
      float v0 = acc[t][u][0], v1 = acc[t][u][1], v2 = acc[t][u][2], v3 = acc[t][u][3];
#pragma unroll
      for (int s = 1; s < 16; s <<= 1) {
        v0 += __shfl_xor(v0, s);
        v1 += __shfl_xor(v1, s);
        v2 += __shfl_xor(v2, s);
        v3 += __shfl_xor(v3, s);
      }
      if (lane15 < 4) {
        float val = (lane15 == 0) ? v0 : (lane15 == 1) ? v1 : (lane15 == 2) ? v2 : v3;
        int m = out_row_base + t * 16 + quad * 4 + lane15;
        pooled[(size_t)m * 512 + g_base + u] = val;
      }
    }
  }
}

__global__ void finalize(const float* __restrict__ pooled,
                         const float* __restrict__ bpool,
                         float* __restrict__ out) {
  int row = blockIdx.x;
  int lane = threadIdx.x;  // 64
  const float* pr = pooled + (size_t)row * 512;
  float mx = -INFINITY;
#pragma unroll
  for (int j = 0; j < 8; ++j) {
    int g = lane + j * 64;
    float p = (pr[g] + bpool[g]) * 0.0625f;  // pooled mean (dot-sum + bias-sum)/16
    float t = tanhf(0.7978845608028654f * (p + 0.044715f * p * p * p));
    mx = fmaxf(mx, p * (1.0f + t));  // gelu_tanh(p) * 2
  }
#pragma unroll
  for (int s = 32; s >= 1; s >>= 1) mx = fmaxf(mx, __shfl_xor(mx, s));
  if (lane == 0) out[row] = mx;
}

extern "C" void kernel_launch(void* const* d_in, const int* in_sizes, int n_in,
                              void* d_out, int out_size, void* d_ws, size_t ws_size,
                              hipStream_t stream) {
  const float* x = (const float*)d_in[0];  // [4096,8192]
  const float* W = (const float*)d_in[1];  // [8192,8192]
  const float* b = (const float*)d_in[2];  // [8192]
  float* out = (float*)d_out;              // [4096]

  char* ws = (char*)d_ws;
  unsigned short* Wb = (unsigned short*)ws;                          // 128 MiB
  unsigned short* xb = (unsigned short*)(ws + (size_t)134217728);    //  64 MiB
  float* pooled = (float*)(ws + (size_t)201326592);                  //   8 MiB
  float* bpool  = (float*)(ws + (size_t)209715200);                  //   2 KiB

  convert_f32_bf16<<<2048, 256, 0, stream>>>((const float4*)W, (ushort4*)Wb,
                                             (N_DIM * K_DIM) / 4);
  convert_f32_bf16<<<2048, 256, 0, stream>>>((const float4*)x, (ushort4*)xb,
                                             (M_DIM * K_DIM) / 4);
  bias_pool<<<1, 512, 0, stream>>>(b, bpool);

  dim3 grid(N_DIM / 128, M_DIM / 128);  // (64, 32)
  gemm_pool<<<grid, 256, 0, stream>>>(xb, Wb, pooled);

  finalize<<<M_DIM, 64, 0, stream>>>(pooled, bpool, out);
}

// Round 3
// 515.072 us; speedup vs baseline: 2.0029x; 2.0029x over previous
//
#include <hip/hip_runtime.h>
#include <hip/hip_bf16.h>
#include <cmath>

// y = x[4096,8192] @ W[8192,8192]^T + b; avgpool16 -> gelu_tanh*2 -> rowmax
// Key algebra: avgpool over OUT features commutes with the GEMM:
//   pooled = x @ Wp^T  where Wp[g,:] = sum of W rows 16g..16g+15  (then /16 later)
// -> GEMM is 4096 x 512 x 8192 (16x fewer FLOPs than naive).
#define M_DIM 4096
#define N_POOL 512
#define K_DIM 8192
#define KSPLIT 8
#define K_PER (K_DIM / KSPLIT)  // 1024

typedef __bf16 bf16x8 __attribute__((ext_vector_type(8)));
typedef float floatx4 __attribute__((ext_vector_type(4)));
typedef unsigned short ushort8v __attribute__((ext_vector_type(8)));

__device__ __forceinline__ unsigned short f2bf(float f) {
  unsigned int u = __float_as_uint(f);
  return (unsigned short)((u + 0x7fffu + ((u >> 16) & 1u)) >> 16);  // RNE
}

// x fp32 -> bf16, 32B read / 16B write per thread-iter
__global__ void convert_f32_bf16(const float4* __restrict__ src,
                                 ushort8v* __restrict__ dst, int n8) {
  int i = blockIdx.x * blockDim.x + threadIdx.x;
  int stride = gridDim.x * blockDim.x;
  for (; i < n8; i += stride) {
    float4 a = src[2 * i], b = src[2 * i + 1];
    ushort8v o;
    o[0] = f2bf(a.x); o[1] = f2bf(a.y); o[2] = f2bf(a.z); o[3] = f2bf(a.w);
    o[4] = f2bf(b.x); o[5] = f2bf(b.y); o[6] = f2bf(b.z); o[7] = f2bf(b.w);
    dst[i] = o;
  }
}

// Wp[g,k] = sum_{j=16g..16g+15} W[j,k], fp32 accumulate, bf16 store.
__global__ void wpool_kernel(const float* __restrict__ W,
                             unsigned short* __restrict__ Wp) {
  int g = blockIdx.x;  // 512
  const float* base = W + (size_t)g * 16 * K_DIM;
  ushort4* out = (ushort4*)(Wp + (size_t)g * K_DIM);
  for (int c4 = threadIdx.x; c4 < K_DIM / 4; c4 += blockDim.x) {
    float4 s = {0.f, 0.f, 0.f, 0.f};
#pragma unroll
    for (int j = 0; j < 16; ++j) {
      float4 v = ((const float4*)(base + (size_t)j * K_DIM))[c4];
      s.x += v.x; s.y += v.y; s.z += v.z; s.w += v.w;
    }
    ushort4 o;
    o.x = f2bf(s.x); o.y = f2bf(s.y); o.z = f2bf(s.z); o.w = f2bf(s.w);
    out[c4] = o;
  }
}

__global__ void bias_pool(const float* __restrict__ b, float* __restrict__ bpool) {
  int g = threadIdx.x;  // 512 groups
  float s = 0.f;
  for (int i = 0; i < 16; ++i) s += b[g * 16 + i];
  bpool[g] = s;
}

// Split-K GEMM: C_part[kz] = x[:, kz*1024:(kz+1)*1024] @ Wp[:, same]^T
// 128x128 tile, BK=64, 4 waves of 64x64, mfma_f32_16x16x32_bf16,
// global_load_lds width=16 staging with XOR bank swizzle (proven R1 structure).
__global__ __launch_bounds__(256) void gemm_splitk(
    const unsigned short* __restrict__ xb,   // [4096][8192] bf16
    const unsigned short* __restrict__ wp,   // [512][8192] bf16
    float* __restrict__ part)                // [KSPLIT][4096][512] fp32
{
  __shared__ __align__(16) unsigned short As[128 * 64];
  __shared__ __align__(16) unsigned short Bs[128 * 64];

  const int tid = threadIdx.x;
  const int L = tid & 63;
  const int w = tid >> 6;
  const int wm = w & 1, wn = w >> 1;
  const int lane15 = L & 15, quad = L >> 4;

  const int bn = blockIdx.x, bm = blockIdx.y, kz = blockIdx.z;

  const int srow = w * 32 + (L >> 3);
  const int schunk = ((L & 7) ^ ((L >> 3) & 7)) * 8;
  const unsigned short* ga = xb + (size_t)(bm * 128 + srow) * K_DIM + kz * K_PER + schunk;
  const unsigned short* gb = wp + (size_t)(bn * 128 + srow) * K_DIM + kz * K_PER + schunk;
  unsigned short* lA = As + (w * 32) * 64;
  unsigned short* lB = Bs + (w * 32) * 64;

  floatx4 acc[4][4];
#pragma unroll
  for (int t = 0; t < 4; ++t)
#pragma unroll
    for (int u = 0; u < 4; ++u) acc[t][u] = (floatx4)0.f;

  const bf16x8* Av = (const bf16x8*)As;
  const bf16x8* Bv = (const bf16x8*)Bs;

  for (int kk = 0; kk < K_PER / 64; ++kk) {
#pragma unroll
    for (int i = 0; i < 4; ++i) {
      __builtin_amdgcn_global_load_lds(
          (const __attribute__((address_space(1))) void*)(ga + (size_t)(i * 8) * K_DIM),
          (__attribute__((address_space(3))) void*)(lA + i * 8 * 64), 16, 0, 0);
    }
#pragma unroll
    for (int i = 0; i < 4; ++i) {
      __builtin_amdgcn_global_load_lds(
          (const __attribute__((address_space(1))) void*)(gb + (size_t)(i * 8) * K_DIM),
          (__attribute__((address_space(3))) void*)(lB + i * 8 * 64), 16, 0, 0);
    }
    ga += 64; gb += 64;
    __syncthreads();

#pragma unroll
    for (int ks = 0; ks < 2; ++ks) {
      bf16x8 af[4], bfr[4];
#pragma unroll
      for (int t = 0; t < 4; ++t) {
        int r = wm * 64 + t * 16 + lane15;
        af[t] = Av[r * 8 + ((ks * 4 + quad) ^ (lane15 & 7))];
      }
#pragma unroll
      for (int u = 0; u < 4; ++u) {
        int r = wn * 64 + u * 16 + lane15;
        bfr[u] = Bv[r * 8 + ((ks * 4 + quad) ^ (lane15 & 7))];
      }
#pragma unroll
      for (int t = 0; t < 4; ++t)
#pragma unroll
        for (int u = 0; u < 4; ++u)
          acc[t][u] = __builtin_amdgcn_mfma_f32_16x16x32_bf16(af[t], bfr[u],
                                                              acc[t][u], 0, 0, 0);
    }
    __syncthreads();
  }

  // C/D layout: col = lane&15, row = quad*4 + reg.
  float* cp = part + (size_t)kz * M_DIM * N_POOL;
  const int row_base = bm * 128 + wm * 64;
  const int col_base = bn * 128 + wn * 64;
#pragma unroll
  for (int t = 0; t < 4; ++t)
#pragma unroll
    for (int u = 0; u < 4; ++u) {
      int col = col_base + u * 16 + lane15;
#pragma unroll
      for (int r = 0; r < 4; ++r) {
        int row = row_base + t * 16 + quad * 4 + r;
        cp[(size_t)row * N_POOL + col] = acc[t][u][r];
      }
    }
}

__global__ void finalize(const float* __restrict__ part,
                         const float* __restrict__ bpool,
                         float* __restrict__ out) {
  int row = blockIdx.x;
  int lane = threadIdx.x;  // 64
  float mx = -INFINITY;
#pragma unroll
  for (int j = 0; j < 8; ++j) {
    int g = lane + j * 64;
    float s = bpool[g];
#pragma unroll
    for (int kz = 0; kz < KSPLIT; ++kz)
      s += part[(size_t)kz * M_DIM * N_POOL + (size_t)row * N_POOL + g];
    float p = s * 0.0625f;
    float t = tanhf(0.7978845608028654f * (p + 0.044715f * p * p * p));
    mx = fmaxf(mx, p * (1.0f + t));  // gelu_tanh(p) * SCALE(=2)
  }
#pragma unroll
  for (int s = 32; s >= 1; s >>= 1) mx = fmaxf(mx, __shfl_xor(mx, s));
  if (lane == 0) out[row] = mx;
}

extern "C" void kernel_launch(void* const* d_in, const int* in_sizes, int n_in,
                              void* d_out, int out_size, void* d_ws, size_t ws_size,
                              hipStream_t stream) {
  const float* x = (const float*)d_in[0];  // [4096,8192]
  const float* W = (const float*)d_in[1];  // [8192,8192]
  const float* b = (const float*)d_in[2];  // [8192]
  float* out = (float*)d_out;              // [4096]

  // Workspace layout (no overlaps — R2's bug was bpool inside part):
  //   xb    [0,          67108864)   64 MiB  bf16 x
  //   Wp    [67108864,   75497472)    8 MiB  bf16 pooled W
  //   part  [75497472,  142606336)   64 MiB  fp32 split-K partials
  //   bpool [142606336, 142608384)    2 KiB  fp32 pooled bias
  char* ws = (char*)d_ws;
  unsigned short* xb = (unsigned short*)ws;
  unsigned short* Wp = (unsigned short*)(ws + (size_t)67108864);
  float* part = (float*)(ws + (size_t)75497472);
  float* bpool = (float*)(ws + (size_t)142606336);

  wpool_kernel<<<N_POOL, 256, 0, stream>>>(W, Wp);
  convert_f32_bf16<<<2048, 256, 0, stream>>>((const float4*)x, (ushort8v*)xb,
                                             (M_DIM * K_DIM) / 8);
  bias_pool<<<1, 512, 0, stream>>>(b, bpool);

  dim3 grid(N_POOL / 128, M_DIM / 128, KSPLIT);  // (4, 32, 8)
  gemm_splitk<<<grid, 256, 0, stream>>>(xb, Wp, part);

  finalize<<<M_DIM, 64, 0, stream>>>(part, bpool, out);
}